// Round 14
// baseline (205.621 us; speedup 1.0000x reference)
//
#include <hip/hip_runtime.h>
#include <hip/hip_bf16.h>
#include <cstdint>

#define N_NODES 50000
#define N_EDGES 1600000
#define EE (N_EDGES + N_NODES)
#define BSH 7
#define BSIZE 128
#define NBUCKET ((N_NODES + BSIZE - 1) >> BSH)   // 391
#define CSH 13
#define CAP 8192                                  // pow2 bucket capacity (mean fill 4224)
#define BT 8
#define BCHUNK (256 * BT)                         // 2048 edges per bin block
#define BIN_BLOCKS ((EE + BCHUNK - 1) / BCHUNK)   // 806
#define GEMM_BLOCKS 3125                          // 3125*16 == 50000

__device__ __forceinline__ float lrelu(float x, float s) { return x >= 0.f ? x : s * x; }
__device__ __forceinline__ float bflo(uint32_t v) { return __uint_as_float(v << 16); }
__device__ __forceinline__ float bfhi(uint32_t v) { return __uint_as_float(v & 0xFFFF0000u); }
__device__ __forceinline__ uint32_t packbf(float a, float b) {
    uint32_t ua = __float_as_uint(a), ub = __float_as_uint(b);
    ua += 0x7FFF + ((ua >> 16) & 1);
    ub += 0x7FFF + ((ub >> 16) & 1);
    return (ua >> 16) | (ub & 0xFFFF0000u);
}
__device__ __forceinline__ float rdlane(float v, int l) {
    return __uint_as_float(__builtin_amdgcn_readlane(__float_as_uint(v), l));
}

// -------- Fused: edge binning (blocks 0..805, dispatched first) + layer-1 GEMM (rest) --------
__global__ __launch_bounds__(256) void k_pre(
    const float* __restrict__ x, const float* __restrict__ W1,
    const float* __restrict__ as_w, const float* __restrict__ ad_w,
    uint32_t* __restrict__ h1b, float* __restrict__ as1, float* __restrict__ ad1,
    const int* __restrict__ src, const int* __restrict__ dst,
    int* __restrict__ bcur, uint32_t* __restrict__ binned) {
    if (blockIdx.x < BIN_BLOCKS) {
        __shared__ int lcnt[NBUCKET];
        __shared__ int lbase[NBUCKET];
        for (int i = threadIdx.x; i < NBUCKET; i += 256) lcnt[i] = 0;
        __syncthreads();
        uint32_t pv[BT];
        uint32_t pm[BT];
        int base = blockIdx.x * BCHUNK;
        if (base + BCHUNK <= N_EDGES) {
            // fast path: pure-edge chunk, int4 loads
            const int4* s4 = (const int4*)(src + base);
            const int4* d4 = (const int4*)(dst + base);
#pragma unroll
            for (int k = 0; k < BT / 4; k++) {
                int4 sv = s4[threadIdx.x + k * 256];
                int4 dv = d4[threadIdx.x + k * 256];
                int ss[4] = {sv.x, sv.y, sv.z, sv.w};
                int dd[4] = {dv.x, dv.y, dv.z, dv.w};
#pragma unroll
                for (int j = 0; j < 4; j++) {
                    int b = dd[j] >> BSH;
                    int r = atomicAdd(&lcnt[b], 1);
                    pv[k * 4 + j] = (uint32_t)ss[j] | ((uint32_t)(dd[j] & (BSIZE - 1)) << 16);
                    pm[k * 4 + j] = (uint32_t)r | ((uint32_t)b << 16);
                }
            }
        } else {
#pragma unroll
            for (int k = 0; k < BT; k++) {
                int e = base + k * 256 + threadIdx.x;
                pm[k] = 0xFFFFFFFFu;
                if (e < EE) {
                    int s, d;
                    if (e < N_EDGES) { s = src[e]; d = dst[e]; } else { s = e - N_EDGES; d = s; }
                    int b = d >> BSH;
                    int r = atomicAdd(&lcnt[b], 1);
                    pv[k] = (uint32_t)s | ((uint32_t)(d & (BSIZE - 1)) << 16);
                    pm[k] = (uint32_t)r | ((uint32_t)b << 16);
                }
            }
        }
        __syncthreads();
        for (int i = threadIdx.x; i < NBUCKET; i += 256) {
            int c = lcnt[i];
            if (c) lbase[i] = atomicAdd(&bcur[i], c);
        }
        __syncthreads();
#pragma unroll
        for (int k = 0; k < BT; k++) {
            if (pm[k] != 0xFFFFFFFFu) {
                int b = pm[k] >> 16, r = pm[k] & 0xFFFF;
                binned[((size_t)b << CSH) + lbase[b] + r] = pv[k];
            }
        }
        return;
    }
    // ---- layer-1 GEMM half: coalesced x load + readlane broadcast ----
    int c = threadIdx.x & 63;
    int wv = threadIdx.x >> 6;
    float wreg[64];
#pragma unroll
    for (int k = 0; k < 64; k++) wreg[k] = W1[k * 64 + c];
    float aw = as_w[c];
    float dw = ad_w[c];
    int base = (blockIdx.x - BIN_BLOCKS) * 16 + wv * 4;
#pragma unroll
    for (int r = 0; r < 4; r++) {
        int n = base + r;
        float xr = x[n * 64 + c];
        float a0 = 0.f, a1 = 0.f, a2 = 0.f, a3 = 0.f;
#pragma unroll
        for (int k = 0; k < 64; k += 4) {
            a0 = fmaf(rdlane(xr, k),     wreg[k],     a0);
            a1 = fmaf(rdlane(xr, k + 1), wreg[k + 1], a1);
            a2 = fmaf(rdlane(xr, k + 2), wreg[k + 2], a2);
            a3 = fmaf(rdlane(xr, k + 3), wreg[k + 3], a3);
        }
        float acc = (a0 + a1) + (a2 + a3);
        float other = __shfl_xor(acc, 1, 64);
        if (!(c & 1)) h1b[n * 32 + (c >> 1)] = packbf(acc, other);
        float asv = acc * aw;
        float adv = acc * dw;
#pragma unroll
        for (int off = 1; off < 16; off <<= 1) {
            asv += __shfl_xor(asv, off, 64);
            adv += __shfl_xor(adv, off, 64);
        }
        if ((c & 15) == 0) { as1[n * 4 + (c >> 4)] = asv; ad1[n * 4 + (c >> 4)] = adv; }
    }
}

// -------- Phase B: rank-capture counting sort (1024 thr) -> u16 CSR src indices --------
// rowdesc[node] = off(13b) | deg(<<13);  esrc[pos] = src (u16)
__global__ __launch_bounds__(1024) void kB_sort(const int* __restrict__ bcur, const uint32_t* __restrict__ binned,
                                                int* __restrict__ rowdesc, unsigned short* __restrict__ esrc) {
    int b = blockIdx.x, tid = threadIdx.x, wv = tid >> 6;   // 16 waves
    int p0 = b << CSH;
    int L = bcur[b];
    __shared__ int cnt16[16][BSIZE];    // per-wave histograms
    __shared__ int wbase[16][BSIZE];
    __shared__ int shs[BSIZE];
    for (int i = tid; i < 16 * BSIZE; i += 1024) ((int*)cnt16)[i] = 0;
    __syncthreads();

    uint32_t pv[8];
    unsigned short rk[8];
#pragma unroll
    for (int k = 0; k < 8; k++) {
        int i = tid + k * 1024;
        if (i < L) {
            uint32_t v = binned[p0 + i];
            pv[k] = v;
            rk[k] = (unsigned short)atomicAdd(&cnt16[wv][(v >> 16) & (BSIZE - 1)], 1);
        }
    }
    __syncthreads();

    int tot = 0;
    if (tid < BSIZE) {
#pragma unroll
        for (int w = 0; w < 16; w++) tot += cnt16[w][tid];
        shs[tid] = tot;
    }
    __syncthreads();
    for (int off = 1; off < BSIZE; off <<= 1) {
        int t = 0;
        if (tid < BSIZE && tid >= off) t = shs[tid - off];
        __syncthreads();
        if (tid < BSIZE && tid >= off) shs[tid] += t;
        __syncthreads();
    }
    if (tid < BSIZE) {
        int excl = shs[tid] - tot;
        int node = (b << BSH) + tid;
        if (node < N_NODES) rowdesc[node] = excl | (tot << 13);
        int wb = excl;
#pragma unroll
        for (int w = 0; w < 16; w++) { wbase[w][tid] = wb; wb += cnt16[w][tid]; }
    }
    __syncthreads();

#pragma unroll
    for (int k = 0; k < 8; k++) {
        int i = tid + k * 1024;
        if (i < L) {
            uint32_t v = pv[k];
            int dl = (v >> 16) & (BSIZE - 1);
            esrc[p0 + wbase[wv][dl] + (int)rk[k]] = (unsigned short)(v & 0xFFFF);
        }
    }
}

// -------- Layer 1 aggregation (inline weights, peeled tail) + fused L2 GEMM --------
__global__ __launch_bounds__(256) void k_aggr1f(
    const int* __restrict__ rowdesc, const unsigned short* __restrict__ esrc,
    const float* __restrict__ as1, const float* __restrict__ ad1,
    const uint32_t* __restrict__ h1b,
    const float* __restrict__ b1, const float* __restrict__ W2,
    const float* __restrict__ as2w, const float* __restrict__ ad2w,
    float* __restrict__ h2, float* __restrict__ as2, float* __restrict__ ad2) {
    int n = blockIdx.x * 4 + (threadIdx.x >> 6);
    int lane = threadIdx.x & 63;
    int md = rowdesc[n];
    int begin = ((n >> BSH) << CSH) + (md & (CAP - 1));
    int deg = md >> 13;

    int slot = lane >> 3, cl = lane & 7;   // edge slot = slot; lane covers channels 8cl..8cl+7
    int hc = cl >> 1;                      // head of these channels
    float ad1h = ad1[n * 4 + hc];

    const uint4* h1b4 = (const uint4*)h1b;
    float a0 = 0.f, a1 = 0.f, a2 = 0.f, a3 = 0.f, a4 = 0.f, a5 = 0.f, a6 = 0.f, a7 = 0.f, dsum = 0.f;

    int full = deg >> 3, rem = deg & 7;
#pragma unroll 4
    for (int it = 0; it < full; it++) {
        int idx = it * 8 + slot;
        int s = esrc[begin + idx];
        float e = as1[s * 4 + hc] + ad1h;
        float w = __expf(e >= 0.f ? e : 0.2f * e);
        uint4 v = h1b4[s * 8 + cl];
        dsum += w;
        a0 += w * bflo(v.x); a1 += w * bfhi(v.x);
        a2 += w * bflo(v.y); a3 += w * bfhi(v.y);
        a4 += w * bflo(v.z); a5 += w * bfhi(v.z);
        a6 += w * bflo(v.w); a7 += w * bfhi(v.w);
    }
    if (rem) {
        int idx = full * 8 + slot;
        int s = esrc[begin + idx];
        float e = as1[s * 4 + hc] + ad1h;
        float w = __expf(e >= 0.f ? e : 0.2f * e);
        w = (slot < rem) ? w : 0.f;
        uint4 v = h1b4[s * 8 + cl];
        dsum += w;
        a0 += w * bflo(v.x); a1 += w * bfhi(v.x);
        a2 += w * bflo(v.y); a3 += w * bfhi(v.y);
        a4 += w * bflo(v.z); a5 += w * bfhi(v.z);
        a6 += w * bflo(v.w); a7 += w * bfhi(v.w);
    }
#pragma unroll
    for (int off = 8; off <= 32; off <<= 1) {
        a0 += __shfl_xor(a0, off, 64); a1 += __shfl_xor(a1, off, 64);
        a2 += __shfl_xor(a2, off, 64); a3 += __shfl_xor(a3, off, 64);
        a4 += __shfl_xor(a4, off, 64); a5 += __shfl_xor(a5, off, 64);
        a6 += __shfl_xor(a6, off, 64); a7 += __shfl_xor(a7, off, 64);
        dsum += __shfl_xor(dsum, off, 64);
    }
    float dinv = 1.f / dsum;               // full denom of head hc

    float4 bb0 = *(const float4*)(b1 + 8 * cl);
    float4 bb1 = *(const float4*)(b1 + 8 * cl + 4);
    float act0 = lrelu(a0 * dinv + bb0.x, 0.01f);
    float act1 = lrelu(a1 * dinv + bb0.y, 0.01f);
    float act2 = lrelu(a2 * dinv + bb0.z, 0.01f);
    float act3 = lrelu(a3 * dinv + bb0.w, 0.01f);
    float act4 = lrelu(a4 * dinv + bb1.x, 0.01f);
    float act5 = lrelu(a5 * dinv + bb1.y, 0.01f);
    float act6 = lrelu(a6 * dinv + bb1.z, 0.01f);
    float act7 = lrelu(a7 * dinv + bb1.w, 0.01f);

    // fused L2 GEMM: lane (kg, co) sums k = 16kg..16kg+15 for output channel co
    int co = lane & 15, kg = lane >> 4;
    int l0 = 2 * kg, l1 = 2 * kg + 1;
    const float* w2r = W2 + (16 * kg) * 16 + co;
    float g = 0.f;
    g = fmaf(__shfl(act0, l0, 64), w2r[0 * 16],  g);
    g = fmaf(__shfl(act1, l0, 64), w2r[1 * 16],  g);
    g = fmaf(__shfl(act2, l0, 64), w2r[2 * 16],  g);
    g = fmaf(__shfl(act3, l0, 64), w2r[3 * 16],  g);
    g = fmaf(__shfl(act4, l0, 64), w2r[4 * 16],  g);
    g = fmaf(__shfl(act5, l0, 64), w2r[5 * 16],  g);
    g = fmaf(__shfl(act6, l0, 64), w2r[6 * 16],  g);
    g = fmaf(__shfl(act7, l0, 64), w2r[7 * 16],  g);
    g = fmaf(__shfl(act0, l1, 64), w2r[8 * 16],  g);
    g = fmaf(__shfl(act1, l1, 64), w2r[9 * 16],  g);
    g = fmaf(__shfl(act2, l1, 64), w2r[10 * 16], g);
    g = fmaf(__shfl(act3, l1, 64), w2r[11 * 16], g);
    g = fmaf(__shfl(act4, l1, 64), w2r[12 * 16], g);
    g = fmaf(__shfl(act5, l1, 64), w2r[13 * 16], g);
    g = fmaf(__shfl(act6, l1, 64), w2r[14 * 16], g);
    g = fmaf(__shfl(act7, l1, 64), w2r[15 * 16], g);
    g += __shfl_xor(g, 16, 64);
    g += __shfl_xor(g, 32, 64);
    if (lane < 16) h2[n * 16 + co] = g;
    float asv = g * as2w[co];
    float adv2 = g * ad2w[co];
#pragma unroll
    for (int off = 1; off < 16; off <<= 1) {
        asv += __shfl_xor(asv, off, 64);
        adv2 += __shfl_xor(adv2, off, 64);
    }
    if (lane == 0) { as2[n] = asv; ad2[n] = adv2; }
}

// -------- Layer 2 aggregation (inline weights, peeled tail) + final linear --------
__global__ __launch_bounds__(256) void k_aggr2(
    const int* __restrict__ rowdesc, const unsigned short* __restrict__ esrc,
    const float* __restrict__ as2, const float* __restrict__ ad2,
    const float* __restrict__ h2,
    const float* __restrict__ b2, const float* __restrict__ Wo,
    const float* __restrict__ bo, float* __restrict__ out) {
    int n = blockIdx.x * 4 + (threadIdx.x >> 6);
    int lane = threadIdx.x & 63;
    int md = rowdesc[n];
    int begin = ((n >> BSH) << CSH) + (md & (CAP - 1));
    int deg = md >> 13;
    float adv = ad2[n];

    int slot = lane >> 3, c2 = lane & 7;   // lane covers channels 2c2, 2c2+1
    const float2* h22 = (const float2*)h2;
    float acc0 = 0.f, acc1 = 0.f, dsum = 0.f;

    int full = deg >> 3, rem = deg & 7;
#pragma unroll 4
    for (int it = 0; it < full; it++) {
        int idx = it * 8 + slot;
        int s = esrc[begin + idx];
        float e = as2[s] + adv;
        float w = __expf(e >= 0.f ? e : 0.2f * e);
        float2 hv = h22[s * 8 + c2];
        acc0 += w * hv.x;
        acc1 += w * hv.y;
        dsum += w;
    }
    if (rem) {
        int idx = full * 8 + slot;
        int s = esrc[begin + idx];
        float e = as2[s] + adv;
        float w = __expf(e >= 0.f ? e : 0.2f * e);
        w = (slot < rem) ? w : 0.f;
        float2 hv = h22[s * 8 + c2];
        acc0 += w * hv.x;
        acc1 += w * hv.y;
        dsum += w;
    }
#pragma unroll
    for (int off = 8; off <= 32; off <<= 1) {
        acc0 += __shfl_xor(acc0, off, 64);
        acc1 += __shfl_xor(acc1, off, 64);
        dsum += __shfl_xor(dsum, off, 64);
    }
    float v0 = lrelu(acc0 / dsum + b2[2 * c2], 0.01f) * Wo[2 * c2];
    float v1 = lrelu(acc1 / dsum + b2[2 * c2 + 1], 0.01f) * Wo[2 * c2 + 1];
    float y = v0 + v1;
    y += __shfl_xor(y, 1, 64);
    y += __shfl_xor(y, 2, 64);
    y += __shfl_xor(y, 4, 64);
    if (lane == 0) out[n] = y + bo[0];
}

extern "C" void kernel_launch(void* const* d_in, const int* in_sizes, int n_in,
                              void* d_out, int out_size, void* d_ws, size_t ws_size,
                              hipStream_t stream) {
    const float* x    = (const float*)d_in[0];
    const int*   ei   = (const int*)d_in[1];
    const float* W1   = (const float*)d_in[2];
    const float* as1w = (const float*)d_in[3];
    const float* ad1w = (const float*)d_in[4];
    const float* b1   = (const float*)d_in[5];
    const float* W2   = (const float*)d_in[6];
    const float* as2w = (const float*)d_in[7];
    const float* ad2w = (const float*)d_in[8];
    const float* b2   = (const float*)d_in[9];
    const float* Wo   = (const float*)d_in[10];
    const float* bo   = (const float*)d_in[11];
    float* out = (float*)d_out;

    const int* srcp = ei;
    const int* dstp = ei + N_EDGES;

    char* p = (char*)d_ws;
    auto alloc = [&](size_t bytes) -> char* {
        char* r = p;
        p += (bytes + 255) / 256 * 256;
        return r;
    };
    // layout safety for masked tail gathers (garbage s <= 65535):
    //   h2 gather reaches <=4.2MB past h2 start  -> h1b (6.4MB) follows  OK
    //   h1b gather reaches <=8.4MB past h1b start -> as1/ad1/as2/ad2 + 4MB pad follow  OK
    int*            bcur    = (int*)alloc((size_t)(NBUCKET + 1) * 4);
    int*            rowdesc = (int*)alloc((size_t)N_NODES * 4);
    uint32_t*       binned  = (uint32_t*)alloc((size_t)NBUCKET * CAP * 4);
    unsigned short* esrc    = (unsigned short*)alloc((size_t)NBUCKET * CAP * 2 + 256);
    float*          h2      = (float*)alloc((size_t)N_NODES * 16 * 4);
    uint32_t*       h1b     = (uint32_t*)alloc((size_t)N_NODES * 32 * 4);
    float*          as1     = (float*)alloc((size_t)N_NODES * 4 * 4);
    float*          ad1     = (float*)alloc((size_t)N_NODES * 4 * 4);
    float*          as2     = (float*)alloc((size_t)N_NODES * 4);
    float*          ad2     = (float*)alloc((size_t)N_NODES * 4);
    (void)alloc(4 * 1024 * 1024);   // safety pad for masked tail gathers

    hipMemsetAsync(bcur, 0, (size_t)(NBUCKET + 1) * 4, stream);

    k_pre<<<BIN_BLOCKS + GEMM_BLOCKS, 256, 0, stream>>>(x, W1, as1w, ad1w, h1b, as1, ad1,
                                                        srcp, dstp, bcur, binned);
    kB_sort<<<NBUCKET, 1024, 0, stream>>>(bcur, binned, rowdesc, esrc);
    k_aggr1f<<<N_NODES / 4, 256, 0, stream>>>(rowdesc, esrc, as1, ad1, h1b, b1, W2, as2w, ad2w, h2, as2, ad2);
    k_aggr2<<<N_NODES / 4, 256, 0, stream>>>(rowdesc, esrc, as2, ad2, h2, b2, Wo, bo, out);
}

// Round 15
// 193.137 us; speedup vs baseline: 1.0646x; 1.0646x over previous
//
#include <hip/hip_runtime.h>
#include <hip/hip_bf16.h>
#include <cstdint>

#define N_NODES 50000
#define N_EDGES 1600000
#define EE (N_EDGES + N_NODES)
#define BSH 7
#define BSIZE 128
#define NBUCKET ((N_NODES + BSIZE - 1) >> BSH)   // 391
#define CSH 13
#define CAP 8192                                  // pow2 bucket capacity (mean fill 4224)
#define BIN_BLOCKS 403                            // ceil(EE/4096) -- one chunk per block
#define GEMM_BLOCKS 3125                          // 3125*16 == 50000

__device__ __forceinline__ float lrelu(float x, float s) { return x >= 0.f ? x : s * x; }
__device__ __forceinline__ float bflo(uint32_t v) { return __uint_as_float(v << 16); }
__device__ __forceinline__ float bfhi(uint32_t v) { return __uint_as_float(v & 0xFFFF0000u); }
__device__ __forceinline__ uint32_t packbf(float a, float b) {
    uint32_t ua = __float_as_uint(a), ub = __float_as_uint(b);
    ua += 0x7FFF + ((ua >> 16) & 1);
    ub += 0x7FFF + ((ub >> 16) & 1);
    return (ua >> 16) | (ub & 0xFFFF0000u);
}
__device__ __forceinline__ float rdlane(float v, int l) {
    return __uint_as_float(__builtin_amdgcn_readlane(__float_as_uint(v), l));
}

// -------- Fused: edge binning (blocks 0..402, dispatched first) + layer-1 GEMM (rest) --------
__global__ __launch_bounds__(256) void k_pre(
    const float* __restrict__ x, const float* __restrict__ W1,
    const float* __restrict__ as_w, const float* __restrict__ ad_w,
    uint32_t* __restrict__ h1b, float* __restrict__ as1, float* __restrict__ ad1,
    const int* __restrict__ src, const int* __restrict__ dst,
    int* __restrict__ bcur, uint32_t* __restrict__ binned) {
    if (blockIdx.x < BIN_BLOCKS) {
        __shared__ int lcnt[NBUCKET];
        __shared__ int lbase[NBUCKET];
        const int T = 16;
        for (int i = threadIdx.x; i < NBUCKET; i += 256) lcnt[i] = 0;
        __syncthreads();
        uint32_t pv[T];
        uint32_t pm[T];
        int base = blockIdx.x * (256 * T);
        if (base + 256 * T <= N_EDGES) {
            // fast path: pure-edge chunk, int4 loads (4 edges per load)
            const int4* s4 = (const int4*)(src + base);
            const int4* d4 = (const int4*)(dst + base);
#pragma unroll
            for (int k = 0; k < 4; k++) {
                int4 sv = s4[threadIdx.x + k * 256];
                int4 dv = d4[threadIdx.x + k * 256];
                int ss[4] = {sv.x, sv.y, sv.z, sv.w};
                int dd[4] = {dv.x, dv.y, dv.z, dv.w};
#pragma unroll
                for (int j = 0; j < 4; j++) {
                    int b = dd[j] >> BSH;
                    int r = atomicAdd(&lcnt[b], 1);
                    pv[k * 4 + j] = (uint32_t)ss[j] | ((uint32_t)(dd[j] & (BSIZE - 1)) << 16);
                    pm[k * 4 + j] = (uint32_t)r | ((uint32_t)b << 16);
                }
            }
        } else {
#pragma unroll
            for (int k = 0; k < T; k++) {
                int e = base + ((k & 3) * 4 + (k >> 2)) * 256 + threadIdx.x;  // any order ok
                pm[k] = 0xFFFFFFFFu;
                if (e < EE) {
                    int s, d;
                    if (e < N_EDGES) { s = src[e]; d = dst[e]; } else { s = e - N_EDGES; d = s; }
                    int b = d >> BSH;
                    int r = atomicAdd(&lcnt[b], 1);
                    pv[k] = (uint32_t)s | ((uint32_t)(d & (BSIZE - 1)) << 16);
                    pm[k] = (uint32_t)r | ((uint32_t)b << 16);
                }
            }
        }
        __syncthreads();
        for (int i = threadIdx.x; i < NBUCKET; i += 256) {
            int c = lcnt[i];
            if (c) lbase[i] = atomicAdd(&bcur[i], c);
        }
        __syncthreads();
#pragma unroll
        for (int k = 0; k < T; k++) {
            if (pm[k] != 0xFFFFFFFFu) {
                int b = pm[k] >> 16, r = pm[k] & 0xFFFF;
                binned[((size_t)b << CSH) + lbase[b] + r] = pv[k];
            }
        }
        return;
    }
    // ---- layer-1 GEMM half: coalesced x load + readlane broadcast ----
    int c = threadIdx.x & 63;
    int wv = threadIdx.x >> 6;
    float wreg[64];
#pragma unroll
    for (int k = 0; k < 64; k++) wreg[k] = W1[k * 64 + c];
    float aw = as_w[c];
    float dw = ad_w[c];
    int base = (blockIdx.x - BIN_BLOCKS) * 16 + wv * 4;
#pragma unroll
    for (int r = 0; r < 4; r++) {
        int n = base + r;
        float xr = x[n * 64 + c];
        float a0 = 0.f, a1 = 0.f, a2 = 0.f, a3 = 0.f;
#pragma unroll
        for (int k = 0; k < 64; k += 4) {
            a0 = fmaf(rdlane(xr, k),     wreg[k],     a0);
            a1 = fmaf(rdlane(xr, k + 1), wreg[k + 1], a1);
            a2 = fmaf(rdlane(xr, k + 2), wreg[k + 2], a2);
            a3 = fmaf(rdlane(xr, k + 3), wreg[k + 3], a3);
        }
        float acc = (a0 + a1) + (a2 + a3);
        float other = __shfl_xor(acc, 1, 64);
        if (!(c & 1)) h1b[n * 32 + (c >> 1)] = packbf(acc, other);
        float asv = acc * aw;
        float adv = acc * dw;
#pragma unroll
        for (int off = 1; off < 16; off <<= 1) {
            asv += __shfl_xor(asv, off, 64);
            adv += __shfl_xor(adv, off, 64);
        }
        if ((c & 15) == 0) { as1[n * 4 + (c >> 4)] = asv; ad1[n * 4 + (c >> 4)] = adv; }
    }
}

// -------- Phase B: rank-capture counting sort -> u16 CSR src indices --------
// rowdesc[node] = off(13b) | deg(<<13);  esrc[pos] = src (u16)
__global__ __launch_bounds__(512) void kB_sort(const int* __restrict__ bcur, const uint32_t* __restrict__ binned,
                                               int* __restrict__ rowdesc, unsigned short* __restrict__ esrc) {
    int b = blockIdx.x, tid = threadIdx.x, wv = tid >> 6;
    int p0 = b << CSH;
    int L = bcur[b];
    __shared__ int cnt8[8][BSIZE];     // per-wave histograms
    __shared__ int wbase[8][BSIZE];
    __shared__ int shs[BSIZE];
    for (int i = tid; i < 8 * BSIZE; i += 512) ((int*)cnt8)[i] = 0;
    __syncthreads();

    uint32_t pv[16];
    unsigned short rk[16];
#pragma unroll
    for (int k = 0; k < 16; k++) {
        int i = tid + k * 512;
        if (i < L) {
            uint32_t v = binned[p0 + i];
            pv[k] = v;
            rk[k] = (unsigned short)atomicAdd(&cnt8[wv][(v >> 16) & (BSIZE - 1)], 1);
        }
    }
    __syncthreads();

    int tot = 0;
    if (tid < BSIZE) {
#pragma unroll
        for (int w = 0; w < 8; w++) tot += cnt8[w][tid];
        shs[tid] = tot;
    }
    __syncthreads();
    for (int off = 1; off < BSIZE; off <<= 1) {
        int t = 0;
        if (tid < BSIZE && tid >= off) t = shs[tid - off];
        __syncthreads();
        if (tid < BSIZE && tid >= off) shs[tid] += t;
        __syncthreads();
    }
    if (tid < BSIZE) {
        int excl = shs[tid] - tot;
        int node = (b << BSH) + tid;
        if (node < N_NODES) rowdesc[node] = excl | (tot << 13);
        int wb = excl;
#pragma unroll
        for (int w = 0; w < 8; w++) { wbase[w][tid] = wb; wb += cnt8[w][tid]; }
    }
    __syncthreads();

#pragma unroll
    for (int k = 0; k < 16; k++) {
        int i = tid + k * 512;
        if (i < L) {
            uint32_t v = pv[k];
            int dl = (v >> 16) & (BSIZE - 1);
            esrc[p0 + wbase[wv][dl] + (int)rk[k]] = (unsigned short)(v & 0xFFFF);
        }
    }
}

// -------- Layer 1 aggregation (inline weights) + fused L2 GEMM: 8 edges/iter --------
__global__ __launch_bounds__(256) void k_aggr1f(
    const int* __restrict__ rowdesc, const unsigned short* __restrict__ esrc,
    const float* __restrict__ as1, const float* __restrict__ ad1,
    const uint32_t* __restrict__ h1b,
    const float* __restrict__ b1, const float* __restrict__ W2,
    const float* __restrict__ as2w, const float* __restrict__ ad2w,
    float* __restrict__ h2, float* __restrict__ as2, float* __restrict__ ad2) {
    int n = blockIdx.x * 4 + (threadIdx.x >> 6);
    int lane = threadIdx.x & 63;
    int md = rowdesc[n];
    int begin = ((n >> BSH) << CSH) + (md & (CAP - 1));
    int deg = md >> 13;

    int slot = lane >> 3, cl = lane & 7;   // edge slot = slot; lane covers channels 8cl..8cl+7
    int hc = cl >> 1;                      // head of these channels
    float ad1h = ad1[n * 4 + hc];

    const uint4* h1b4 = (const uint4*)h1b;
    float a0 = 0.f, a1 = 0.f, a2 = 0.f, a3 = 0.f, a4 = 0.f, a5 = 0.f, a6 = 0.f, a7 = 0.f, dsum = 0.f;

    int iters = (deg + 7) >> 3;
#pragma unroll 4
    for (int it = 0; it < iters; it++) {
        int idx = it * 8 + slot;
        int s = esrc[begin + idx];
        float e = as1[s * 4 + hc] + ad1h;
        float w = __expf(e >= 0.f ? e : 0.2f * e);
        w = (idx < deg) ? w : 0.f;
        uint4 v = h1b4[s * 8 + cl];
        dsum += w;
        a0 += w * bflo(v.x); a1 += w * bfhi(v.x);
        a2 += w * bflo(v.y); a3 += w * bfhi(v.y);
        a4 += w * bflo(v.z); a5 += w * bfhi(v.z);
        a6 += w * bflo(v.w); a7 += w * bfhi(v.w);
    }
#pragma unroll
    for (int off = 8; off <= 32; off <<= 1) {
        a0 += __shfl_xor(a0, off, 64); a1 += __shfl_xor(a1, off, 64);
        a2 += __shfl_xor(a2, off, 64); a3 += __shfl_xor(a3, off, 64);
        a4 += __shfl_xor(a4, off, 64); a5 += __shfl_xor(a5, off, 64);
        a6 += __shfl_xor(a6, off, 64); a7 += __shfl_xor(a7, off, 64);
        dsum += __shfl_xor(dsum, off, 64);
    }
    float dinv = 1.f / dsum;               // full denom of head hc

    float4 bb0 = *(const float4*)(b1 + 8 * cl);
    float4 bb1 = *(const float4*)(b1 + 8 * cl + 4);
    float act0 = lrelu(a0 * dinv + bb0.x, 0.01f);
    float act1 = lrelu(a1 * dinv + bb0.y, 0.01f);
    float act2 = lrelu(a2 * dinv + bb0.z, 0.01f);
    float act3 = lrelu(a3 * dinv + bb0.w, 0.01f);
    float act4 = lrelu(a4 * dinv + bb1.x, 0.01f);
    float act5 = lrelu(a5 * dinv + bb1.y, 0.01f);
    float act6 = lrelu(a6 * dinv + bb1.z, 0.01f);
    float act7 = lrelu(a7 * dinv + bb1.w, 0.01f);

    // fused L2 GEMM: lane (kg, co) sums k = 16kg..16kg+15 for output channel co
    int co = lane & 15, kg = lane >> 4;
    int l0 = 2 * kg, l1 = 2 * kg + 1;
    const float* w2r = W2 + (16 * kg) * 16 + co;
    float g = 0.f;
    g = fmaf(__shfl(act0, l0, 64), w2r[0 * 16],  g);
    g = fmaf(__shfl(act1, l0, 64), w2r[1 * 16],  g);
    g = fmaf(__shfl(act2, l0, 64), w2r[2 * 16],  g);
    g = fmaf(__shfl(act3, l0, 64), w2r[3 * 16],  g);
    g = fmaf(__shfl(act4, l0, 64), w2r[4 * 16],  g);
    g = fmaf(__shfl(act5, l0, 64), w2r[5 * 16],  g);
    g = fmaf(__shfl(act6, l0, 64), w2r[6 * 16],  g);
    g = fmaf(__shfl(act7, l0, 64), w2r[7 * 16],  g);
    g = fmaf(__shfl(act0, l1, 64), w2r[8 * 16],  g);
    g = fmaf(__shfl(act1, l1, 64), w2r[9 * 16],  g);
    g = fmaf(__shfl(act2, l1, 64), w2r[10 * 16], g);
    g = fmaf(__shfl(act3, l1, 64), w2r[11 * 16], g);
    g = fmaf(__shfl(act4, l1, 64), w2r[12 * 16], g);
    g = fmaf(__shfl(act5, l1, 64), w2r[13 * 16], g);
    g = fmaf(__shfl(act6, l1, 64), w2r[14 * 16], g);
    g = fmaf(__shfl(act7, l1, 64), w2r[15 * 16], g);
    g += __shfl_xor(g, 16, 64);
    g += __shfl_xor(g, 32, 64);
    if (lane < 16) h2[n * 16 + co] = g;
    float asv = g * as2w[co];
    float adv2 = g * ad2w[co];
#pragma unroll
    for (int off = 1; off < 16; off <<= 1) {
        asv += __shfl_xor(asv, off, 64);
        adv2 += __shfl_xor(adv2, off, 64);
    }
    if (lane == 0) { as2[n] = asv; ad2[n] = adv2; }
}

// -------- Layer 2 aggregation (inline weights) + final linear: 8 edges/iter --------
__global__ __launch_bounds__(256) void k_aggr2(
    const int* __restrict__ rowdesc, const unsigned short* __restrict__ esrc,
    const float* __restrict__ as2, const float* __restrict__ ad2,
    const float* __restrict__ h2,
    const float* __restrict__ b2, const float* __restrict__ Wo,
    const float* __restrict__ bo, float* __restrict__ out) {
    int n = blockIdx.x * 4 + (threadIdx.x >> 6);
    int lane = threadIdx.x & 63;
    int md = rowdesc[n];
    int begin = ((n >> BSH) << CSH) + (md & (CAP - 1));
    int deg = md >> 13;
    float adv = ad2[n];

    int slot = lane >> 3, c2 = lane & 7;   // lane covers channels 2c2, 2c2+1
    const float2* h22 = (const float2*)h2;
    float acc0 = 0.f, acc1 = 0.f, dsum = 0.f;

    int iters = (deg + 7) >> 3;
#pragma unroll 4
    for (int it = 0; it < iters; it++) {
        int idx = it * 8 + slot;
        int s = esrc[begin + idx];
        float e = as2[s] + adv;
        float w = __expf(e >= 0.f ? e : 0.2f * e);
        w = (idx < deg) ? w : 0.f;
        float2 hv = h22[s * 8 + c2];
        acc0 += w * hv.x;
        acc1 += w * hv.y;
        dsum += w;
    }
#pragma unroll
    for (int off = 8; off <= 32; off <<= 1) {
        acc0 += __shfl_xor(acc0, off, 64);
        acc1 += __shfl_xor(acc1, off, 64);
        dsum += __shfl_xor(dsum, off, 64);
    }
    float v0 = lrelu(acc0 / dsum + b2[2 * c2], 0.01f) * Wo[2 * c2];
    float v1 = lrelu(acc1 / dsum + b2[2 * c2 + 1], 0.01f) * Wo[2 * c2 + 1];
    float y = v0 + v1;
    y += __shfl_xor(y, 1, 64);
    y += __shfl_xor(y, 2, 64);
    y += __shfl_xor(y, 4, 64);
    if (lane == 0) out[n] = y + bo[0];
}

extern "C" void kernel_launch(void* const* d_in, const int* in_sizes, int n_in,
                              void* d_out, int out_size, void* d_ws, size_t ws_size,
                              hipStream_t stream) {
    const float* x    = (const float*)d_in[0];
    const int*   ei   = (const int*)d_in[1];
    const float* W1   = (const float*)d_in[2];
    const float* as1w = (const float*)d_in[3];
    const float* ad1w = (const float*)d_in[4];
    const float* b1   = (const float*)d_in[5];
    const float* W2   = (const float*)d_in[6];
    const float* as2w = (const float*)d_in[7];
    const float* ad2w = (const float*)d_in[8];
    const float* b2   = (const float*)d_in[9];
    const float* Wo   = (const float*)d_in[10];
    const float* bo   = (const float*)d_in[11];
    float* out = (float*)d_out;

    const int* srcp = ei;
    const int* dstp = ei + N_EDGES;

    char* p = (char*)d_ws;
    auto alloc = [&](size_t bytes) -> char* {
        char* r = p;
        p += (bytes + 255) / 256 * 256;
        return r;
    };
    // layout safety for masked tail gathers (garbage s <= 65535):
    //   h2 gather reaches <=4.2MB past h2 start  -> h1b (6.4MB) follows  OK
    //   h1b gather reaches <=8.4MB past h1b start -> as1/ad1/as2/ad2 + 4MB pad follow  OK
    int*            bcur    = (int*)alloc((size_t)(NBUCKET + 1) * 4);
    int*            rowdesc = (int*)alloc((size_t)N_NODES * 4);
    uint32_t*       binned  = (uint32_t*)alloc((size_t)NBUCKET * CAP * 4);
    unsigned short* esrc    = (unsigned short*)alloc((size_t)NBUCKET * CAP * 2 + 256);
    float*          h2      = (float*)alloc((size_t)N_NODES * 16 * 4);
    uint32_t*       h1b     = (uint32_t*)alloc((size_t)N_NODES * 32 * 4);
    float*          as1     = (float*)alloc((size_t)N_NODES * 4 * 4);
    float*          ad1     = (float*)alloc((size_t)N_NODES * 4 * 4);
    float*          as2     = (float*)alloc((size_t)N_NODES * 4);
    float*          ad2     = (float*)alloc((size_t)N_NODES * 4);
    (void)alloc(4 * 1024 * 1024);   // safety pad for masked tail gathers

    hipMemsetAsync(bcur, 0, (size_t)(NBUCKET + 1) * 4, stream);

    k_pre<<<BIN_BLOCKS + GEMM_BLOCKS, 256, 0, stream>>>(x, W1, as1w, ad1w, h1b, as1, ad1,
                                                        srcp, dstp, bcur, binned);
    kB_sort<<<NBUCKET, 512, 0, stream>>>(bcur, binned, rowdesc, esrc);
    k_aggr1f<<<N_NODES / 4, 256, 0, stream>>>(rowdesc, esrc, as1, ad1, h1b, b1, W2, as2w, ad2w, h2, as2, ad2);
    k_aggr2<<<N_NODES / 4, 256, 0, stream>>>(rowdesc, esrc, as2, ad2, h2, b2, Wo, bo, out);
}